// Round 12
// baseline (419.480 us; speedup 1.0000x reference)
//
#include <hip/hip_runtime.h>
#include <hip/hip_bf16.h>

#define NN 100000
#define EE 1200000
#define F1 128
#define F2 256
#define F3 40
#define MROWS 64
#define NBUK ((NN + 255) / 256)          // 391 coarse buckets (256 nodes each)
#define NBLK 256                         // scatter blocks (R7-validated shape)
#define CHUNK ((EE + NBLK - 1) / NBLK)   // 4688 edges per block
#define DCAP 4096                        // fixed slots per bucket (mean 3070, +18 sigma)
#define XP8 (NN * 8 / 256)               // 3125 blocks for slice-major x-prep
#define WB ((F1 * F2 + F2 * 48 + 255) / 256)   // 176 weight-pack blocks

typedef __bf16 bf16x8 __attribute__((ext_vector_type(8)));
typedef float  f32x4  __attribute__((ext_vector_type(4)));

__device__ __forceinline__ unsigned short f2bf(float f) {   // RNE bf16
    unsigned u = __float_as_uint(f);
    return (unsigned short)((u + 0x7fffu + ((u >> 16) & 1u)) >> 16);
}
__device__ __forceinline__ float bflo(unsigned v) { return __uint_as_float(v << 16); }
__device__ __forceinline__ float bfhi(unsigned v) { return __uint_as_float(v & 0xffff0000u); }

// ---- launch 1 (scatA ∥ prep ∥ W-pack):
// blocks [0,NBLK): R7-validated hist+reserve+scatter.
// blocks [NBLK,NBLK+XP8): x -> bf16, SLICE-MAJOR xhs[8][NN][8dw] (unscaled;
//   dinv applied in agg1). Slice s = features [16s,16s+16).
// remaining WB blocks: pack W1/W2. ----
__global__ __launch_bounds__(256) void k_scatprep(
    const int* __restrict__ row, const int* __restrict__ col,
    int* __restrict__ bcur, unsigned* __restrict__ rec,
    const float4* __restrict__ x, unsigned* __restrict__ xhs,
    const float* __restrict__ W1, const float* __restrict__ W2,
    __hip_bfloat16* __restrict__ W1p, __hip_bfloat16* __restrict__ W2p) {
    if (blockIdx.x < NBLK) {
        __shared__ int lh[NBUK];     // local count, then local cursor
        __shared__ int lbase[NBUK];  // reserved global base per bucket
        for (int i = threadIdx.x; i < NBUK; i += 256) lh[i] = 0;
        __syncthreads();
        const int e0 = blockIdx.x * CHUNK;
        const int e1 = min(e0 + CHUNK, EE);
        for (int e = e0 + threadIdx.x; e < e1; e += 256) {
            int c = col[e];
            if ((unsigned)c < (unsigned)NN) atomicAdd(&lh[c >> 8], 1);
        }
        __syncthreads();
        for (int i = threadIdx.x; i < NBUK; i += 256) {
            int cn = lh[i];
            lbase[i] = cn ? atomicAdd(&bcur[i], cn) : 0;   // range reservation
            lh[i] = 0;                                     // reuse as cursor
        }
        __syncthreads();
        for (int e = e0 + threadIdx.x; e < e1; e += 256) {
            int r = row[e], c = col[e];                    // col re-read hits L1/L2
            if ((unsigned)c < (unsigned)NN) {
                int b = c >> 8;
                int pos = lbase[b] + atomicAdd(&lh[b], 1); // LDS atomic
                if (pos < DCAP)
                    rec[(size_t)b * DCAP + pos] =
                        ((unsigned)r & 0xFFFFFFu) | ((unsigned)(c & 255) << 24);
            }
        }
    } else if (blockIdx.x < NBLK + XP8) {
        int idx = (blockIdx.x - NBLK) * 256 + threadIdx.x;  // NN*8 exact
        int node = idx >> 3, s = idx & 7;
        const float4* xp = x + (size_t)node * 32 + s * 4;   // 16 floats of slice s
        float4 v0 = xp[0], v1 = xp[1], v2 = xp[2], v3 = xp[3];
        uint4 o0, o1;
        o0.x = (unsigned)f2bf(v0.x) | ((unsigned)f2bf(v0.y) << 16);
        o0.y = (unsigned)f2bf(v0.z) | ((unsigned)f2bf(v0.w) << 16);
        o0.z = (unsigned)f2bf(v1.x) | ((unsigned)f2bf(v1.y) << 16);
        o0.w = (unsigned)f2bf(v1.z) | ((unsigned)f2bf(v1.w) << 16);
        o1.x = (unsigned)f2bf(v2.x) | ((unsigned)f2bf(v2.y) << 16);
        o1.y = (unsigned)f2bf(v2.z) | ((unsigned)f2bf(v2.w) << 16);
        o1.z = (unsigned)f2bf(v3.x) | ((unsigned)f2bf(v3.y) << 16);
        o1.w = (unsigned)f2bf(v3.z) | ((unsigned)f2bf(v3.w) << 16);
        uint4* dst = (uint4*)(xhs + ((size_t)s * NN + node) * 8);
        dst[0] = o0; dst[1] = o1;
    } else {
        int idx = (blockIdx.x - NBLK - XP8) * 256 + threadIdx.x;
        if (idx < F1 * F2) {
            int k = idx / F2, c = idx - (idx / F2) * F2;
            int k8 = k >> 3, j = k & 7;
            W1p[((size_t)(k8 * F2 + c) << 3) + j] = __float2bfloat16(W1[(size_t)k * F2 + c]);
        } else {                               // grid exact: idx < F1*F2 + F2*48
            int i2 = idx - F1 * F2;
            int k = i2 / 48, c = i2 - (i2 / 48) * 48;
            int k8 = k >> 3, j = k & 7;
            float v = (c < F3) ? W2[(size_t)k * F3 + c] : 0.0f;
            W2p[((size_t)(k8 * 48 + c) << 3) + j] = __float2bfloat16(v);
        }
    }
}

// ---- pass 2: bucket -> CSR; rec chunk cached in LDS (single global read);
// cnt via LDS histogram; cursor(end)=b*DCAP+excl+cnt; dinv. ----
__global__ __launch_bounds__(256) void k_csr(const int* __restrict__ bcur,
                                             const unsigned* __restrict__ rec,
                                             int* __restrict__ eidx,
                                             int* __restrict__ cnt,
                                             int* __restrict__ cursor,
                                             float* __restrict__ dinv) {
    __shared__ int lcnt[256];
    __shared__ int s[256];
    __shared__ int lcur[256];
    __shared__ unsigned lrec[DCAP];   // 16 KB cached records
    __shared__ int lde[DCAP];         // 16 KB sorted rows
    const int b = blockIdx.x;
    const int tid = threadIdx.x;
    lcnt[tid] = 0;
    __syncthreads();
    const int base = b * DCAP;
    const int nb = min(bcur[b], DCAP);
    for (int j = tid; j < nb; j += 256) {
        unsigned v = rec[(size_t)base + j];
        lrec[j] = v;
        atomicAdd(&lcnt[v >> 24], 1);
    }
    __syncthreads();
    int cv = lcnt[tid];
    s[tid] = cv;
    __syncthreads();
    int acc = cv;
    for (int d = 1; d < 256; d <<= 1) {
        int add = (tid >= d) ? s[tid - d] : 0;
        __syncthreads();
        acc += add;
        s[tid] = acc;
        __syncthreads();
    }
    int excl = acc - cv;
    lcur[tid] = excl;
    const int node = (b << 8) + tid;
    if (node < NN) {
        cnt[node] = cv;
        cursor[node] = base + excl + cv;            // END cursor (start = end - cnt)
        dinv[node] = rsqrtf((float)(cv + 1));       // +1 self-loop
    }
    __syncthreads();
    for (int j = tid; j < nb; j += 256) {
        unsigned v = lrec[j];
        int pos = atomicAdd(&lcur[v >> 24], 1);     // LDS atomic
        lde[pos] = (int)(v & 0xFFFFFFu);
    }
    __syncthreads();
    for (int j = tid; j < nb; j += 256) eidx[base + j] = lde[j];
}

// ---- layer-1 pull aggregation, XCD-sliced: block (g, s=bid&7) -> XCD s
// (bid%8 round-robin). Wave = one node, slice s; lane=(e,d): 8 edges x 8
// dwords per gather instruction from the L2-RESIDENT 3.2MB slice region.
// shfl_xor reduce over e-groups; lanes e==0 write agg slice-major. ----
__global__ __launch_bounds__(256) void k_agg1(const int* __restrict__ cursor,
                                              const int* __restrict__ cnt,
                                              const int* __restrict__ eidx,
                                              const float* __restrict__ dinv,
                                              const unsigned* __restrict__ xhs,
                                              unsigned* __restrict__ aggs) {
    const int s = blockIdx.x & 7;
    const int g = blockIdx.x >> 3;
    const int wave = threadIdx.x >> 6;
    const int lane = threadIdx.x & 63;
    const int e = lane >> 3, d = lane & 7;
    const int node = g * 4 + wave;                  // NN%4==0, grid exact
    const unsigned* __restrict__ xs = xhs + (size_t)s * (NN * 8);
    const float dn = dinv[node];
    float a0 = 0.f, a1 = 0.f;
    if (e == 0) {                                   // self-loop term
        unsigned vs = xs[(size_t)node * 8 + d];
        a0 = bflo(vs) * dn; a1 = bfhi(vs) * dn;
    }
    const int n = cnt[node];
    const int st = cursor[node] - n;
    int k = e;
    for (; k + 8 < n; k += 16) {                    // 2 gathers in flight/lane
        int r0 = eidx[st + k];
        int r1 = eidx[st + k + 8];
        float d0 = dinv[r0], d1 = dinv[r1];
        unsigned v0 = xs[(size_t)r0 * 8 + d];
        unsigned v1 = xs[(size_t)r1 * 8 + d];
        a0 += bflo(v0) * d0; a1 += bfhi(v0) * d0;
        a0 += bflo(v1) * d1; a1 += bfhi(v1) * d1;
    }
    if (k < n) {
        int r0 = eidx[st + k];
        float d0 = dinv[r0];
        unsigned v0 = xs[(size_t)r0 * 8 + d];
        a0 += bflo(v0) * d0; a1 += bfhi(v0) * d0;
    }
#pragma unroll
    for (int off = 8; off < 64; off <<= 1) {        // reduce over e-groups
        a0 += __shfl_xor(a0, off);
        a1 += __shfl_xor(a1, off);
    }
    if (e == 0)
        aggs[((size_t)s * NN + node) * 8 + d] =
            (unsigned)f2bf(a0 * dn) | ((unsigned)f2bf(a1 * dn) << 16);
}

// ---- fused MFMA GEMM1 + ReLU + GEMM2; A read from slice-major aggs;
// tg rows PACKED to 40 bf16 (80B, 16B-aligned) ----
__global__ __launch_bounds__(256) void k_gemm_mfma(
    const unsigned* __restrict__ aggs, const __hip_bfloat16* __restrict__ W1p,
    const float* __restrict__ b1, const __hip_bfloat16* __restrict__ W2p,
    const float* __restrict__ dinv, unsigned short* __restrict__ tg) {
    __shared__ __hip_bfloat16 h_s[MROWS][F2 + 8];   // 33 KB
    const int i0   = blockIdx.x * MROWS;
    const int wave = threadIdx.x >> 6;
    const int lane = threadIdx.x & 63;
    const int m = lane & 15, q = lane >> 4;
    const int rowA = i0 + wave * 16 + m;

    f32x4 acc[16];
#pragma unroll
    for (int c = 0; c < 16; ++c) acc[c] = (f32x4){0.f, 0.f, 0.f, 0.f};

#pragma unroll
    for (int s = 0; s < 4; ++s) {           // k = 32s + 8q + j -> dwords 16s+4q..+4
        bf16x8 a;
#pragma unroll
        for (int j = 0; j < 8; ++j) a[j] = (__bf16)0.0f;
        if (rowA < NN) {
            const uint4* ap = (const uint4*)(aggs +
                ((size_t)(2 * s + (q >> 1)) * NN + rowA) * 8 + (q & 1) * 4);
            a = __builtin_bit_cast(bf16x8, *ap);
        }
        const __hip_bfloat16* bp = W1p + ((size_t)(4 * s + q) * F2) * 8;
#pragma unroll
        for (int c = 0; c < 16; ++c) {
            bf16x8 b = *(const bf16x8*)(bp + ((size_t)(c * 16 + m) << 3));
            acc[c] = __builtin_amdgcn_mfma_f32_16x16x32_bf16(a, b, acc[c], 0, 0, 0);
        }
    }

#pragma unroll
    for (int c = 0; c < 16; ++c) {
        int col = c * 16 + m;
        float bj = b1[col];
#pragma unroll
        for (int r = 0; r < 4; ++r) {
            int lr = wave * 16 + q * 4 + r;
            h_s[lr][col] = __float2bfloat16(fmaxf(acc[c][r] + bj, 0.0f));
        }
    }
    __syncthreads();

    f32x4 acc2[3];
#pragma unroll
    for (int c = 0; c < 3; ++c) acc2[c] = (f32x4){0.f, 0.f, 0.f, 0.f};

#pragma unroll
    for (int s = 0; s < 8; ++s) {
        bf16x8 a = *(const bf16x8*)(&h_s[wave * 16 + m][s * 32 + q * 8]);
        const __hip_bfloat16* bp = W2p + ((size_t)(4 * s + q) * 48) * 8;
#pragma unroll
        for (int c = 0; c < 3; ++c) {
            bf16x8 b = *(const bf16x8*)(bp + ((size_t)(c * 16 + m) << 3));
            acc2[c] = __builtin_amdgcn_mfma_f32_16x16x32_bf16(a, b, acc2[c], 0, 0, 0);
        }
    }

#pragma unroll
    for (int c = 0; c < 3; ++c) {
        int col = c * 16 + m;
        if (col < F3) {
#pragma unroll
            for (int r = 0; r < 4; ++r) {
                int grow = i0 + wave * 16 + q * 4 + r;
                if (grow < NN)
                    tg[(size_t)grow * F3 + col] = f2bf(acc2[c][r] * dinv[grow]);
            }
        }
    }
}

// ---- layer-2 pull aggregation: 6 nodes/wave (10-lane groups), uint2 per lane
// over packed 80B rows; 3.8KB in flight per wave (R10-validated). ----
__global__ __launch_bounds__(256) void k_agg2(const int* __restrict__ cursor,
                                              const int* __restrict__ cnt,
                                              const int* __restrict__ eidx,
                                              const float* __restrict__ dinv,
                                              const unsigned short* __restrict__ tg,
                                              const float* __restrict__ b2,
                                              float* __restrict__ out) {
    const int wave = threadIdx.x >> 6;
    const int lane = threadIdx.x & 63;
    const int g = lane / 10;                        // 0..6 (6 => idle)
    const int t = lane - g * 10;                    // uint2 index in row
    const int node = blockIdx.x * 24 + wave * 6 + g;
    if (g >= 6 || node >= NN) return;
    const uint2* __restrict__ tg2 = (const uint2*)tg;

    uint2 v = tg2[(size_t)node * 10 + t];           // self term
    float a0 = bflo(v.x), a1 = bfhi(v.x), a2 = bflo(v.y), a3 = bfhi(v.y);
    const int n = cnt[node];
    const int s = cursor[node] - n;
    int k = 0;
    for (; k + 7 < n; k += 8) {
        int r0 = eidx[s + k + 0], r1 = eidx[s + k + 1];
        int r2 = eidx[s + k + 2], r3 = eidx[s + k + 3];
        int r4 = eidx[s + k + 4], r5 = eidx[s + k + 5];
        int r6 = eidx[s + k + 6], r7 = eidx[s + k + 7];
        uint2 v0 = tg2[(size_t)r0 * 10 + t];
        uint2 v1 = tg2[(size_t)r1 * 10 + t];
        uint2 v2 = tg2[(size_t)r2 * 10 + t];
        uint2 v3 = tg2[(size_t)r3 * 10 + t];
        uint2 v4 = tg2[(size_t)r4 * 10 + t];
        uint2 v5 = tg2[(size_t)r5 * 10 + t];
        uint2 v6 = tg2[(size_t)r6 * 10 + t];
        uint2 v7 = tg2[(size_t)r7 * 10 + t];
        a0 += bflo(v0.x); a1 += bfhi(v0.x); a2 += bflo(v0.y); a3 += bfhi(v0.y);
        a0 += bflo(v1.x); a1 += bfhi(v1.x); a2 += bflo(v1.y); a3 += bfhi(v1.y);
        a0 += bflo(v2.x); a1 += bfhi(v2.x); a2 += bflo(v2.y); a3 += bfhi(v2.y);
        a0 += bflo(v3.x); a1 += bfhi(v3.x); a2 += bflo(v3.y); a3 += bfhi(v3.y);
        a0 += bflo(v4.x); a1 += bfhi(v4.x); a2 += bflo(v4.y); a3 += bfhi(v4.y);
        a0 += bflo(v5.x); a1 += bfhi(v5.x); a2 += bflo(v5.y); a3 += bfhi(v5.y);
        a0 += bflo(v6.x); a1 += bfhi(v6.x); a2 += bflo(v6.y); a3 += bfhi(v6.y);
        a0 += bflo(v7.x); a1 += bfhi(v7.x); a2 += bflo(v7.y); a3 += bfhi(v7.y);
    }
    for (; k + 3 < n; k += 4) {
        int r0 = eidx[s + k + 0], r1 = eidx[s + k + 1];
        int r2 = eidx[s + k + 2], r3 = eidx[s + k + 3];
        uint2 v0 = tg2[(size_t)r0 * 10 + t];
        uint2 v1 = tg2[(size_t)r1 * 10 + t];
        uint2 v2 = tg2[(size_t)r2 * 10 + t];
        uint2 v3 = tg2[(size_t)r3 * 10 + t];
        a0 += bflo(v0.x); a1 += bfhi(v0.x); a2 += bflo(v0.y); a3 += bfhi(v0.y);
        a0 += bflo(v1.x); a1 += bfhi(v1.x); a2 += bflo(v1.y); a3 += bfhi(v1.y);
        a0 += bflo(v2.x); a1 += bfhi(v2.x); a2 += bflo(v2.y); a3 += bfhi(v2.y);
        a0 += bflo(v3.x); a1 += bfhi(v3.x); a2 += bflo(v3.y); a3 += bfhi(v3.y);
    }
    for (; k < n; ++k) {
        uint2 v0 = tg2[(size_t)eidx[s + k] * 10 + t];
        a0 += bflo(v0.x); a1 += bfhi(v0.x); a2 += bflo(v0.y); a3 += bfhi(v0.y);
    }
    float d = dinv[node];
    float4 bb = *(const float4*)(b2 + 4 * t);
    float4 o;
    o.x = a0 * d + bb.x;
    o.y = a1 * d + bb.y;
    o.z = a2 * d + bb.z;
    o.w = a3 * d + bb.w;
    *(float4*)(out + (size_t)node * F3 + 4 * t) = o;
}

extern "C" void kernel_launch(void* const* d_in, const int* in_sizes, int n_in,
                              void* d_out, int out_size, void* d_ws, size_t ws_size,
                              hipStream_t stream) {
    const float* x  = (const float*)d_in[0];
    const int*   ei = (const int*)d_in[1];
    const float* W1 = (const float*)d_in[2];
    const float* b1 = (const float*)d_in[3];
    const float* W2 = (const float*)d_in[4];
    const float* b2 = (const float*)d_in[5];
    float* out = (float*)d_out;

    const int* row = ei;
    const int* col = ei + EE;

    // ws: cnt[N] | cursor[N] | dinv[N] | bcur[NBUK] | pad | eidx[NBUK*DCAP]
    //     | xhs[8][N][8] u32 | aggs[8][N][8] u32 | W1p | W2p   ~59 MB
    // overlays: rec (6.4MB) on aggs (dead until k_agg1); tg (8MB) on xhs
    // (dead after k_agg1; agg1/gemm separate launches — round-4 lesson).
    int* cnt     = (int*)d_ws;
    int* cursor  = cnt + NN;
    float* dinv  = (float*)(cursor + NN);
    int* bcur    = (int*)(dinv + NN);
    int* eidx    = bcur + NBUK + 9;            // pad -> 16B alignment
    unsigned* xhs  = (unsigned*)(eidx + NBUK * DCAP);
    unsigned* aggs = xhs + (size_t)NN * 64;
    unsigned* rec = aggs;                              // overlay on aggs (6.4MB)
    unsigned short* tg = (unsigned short*)xhs;         // overlay on xhs (8MB)
    __hip_bfloat16* W1p = (__hip_bfloat16*)(aggs + (size_t)NN * 64);
    __hip_bfloat16* W2p = W1p + (size_t)F1 * F2;

    hipMemsetAsync(bcur, 0, NBUK * sizeof(int), stream);
    k_scatprep<<<NBLK + XP8 + WB, 256, 0, stream>>>(
        row, col, bcur, rec, (const float4*)x, xhs, W1, W2, W1p, W2p);
    k_csr<<<NBUK, 256, 0, stream>>>(bcur, rec, eidx, cnt, cursor, dinv);

    k_agg1<<<(NN / 4) * 8, 256, 0, stream>>>(cursor, cnt, eidx, dinv, xhs, aggs);
    k_gemm_mfma<<<(NN + MROWS - 1) / MROWS, 256, 0, stream>>>(
        aggs, W1p, b1, W2p, dinv, tg);
    k_agg2<<<(NN + 23) / 24, 256, 0, stream>>>(cursor, cnt, eidx, dinv, tg, b2, out);
}

// Round 13
// 265.838 us; speedup vs baseline: 1.5780x; 1.5780x over previous
//
#include <hip/hip_runtime.h>
#include <hip/hip_bf16.h>

#define NN 100000
#define EE 1200000
#define F1 128
#define F2 256
#define F3 40
#define MROWS 64
#define NBUK ((NN + 255) / 256)          // 391 coarse buckets (256 nodes each)
#define NBLK 256                         // scatter blocks (R7-validated shape)
#define CHUNK ((EE + NBLK - 1) / NBLK)   // 4688 edges per block
#define DCAP 4096                        // fixed slots per bucket (mean 3070, +18 sigma)
#define XB2 ((NN * 32 + 255) / 256)      // 12500 blocks for x-prep (float4 granularity)
#define WB ((F1 * F2 + F2 * 48 + 255) / 256)   // 176 weight-pack blocks

typedef __bf16 bf16x8 __attribute__((ext_vector_type(8)));
typedef float  f32x4  __attribute__((ext_vector_type(4)));

__device__ __forceinline__ unsigned short f2bf(float f) {   // RNE bf16
    unsigned u = __float_as_uint(f);
    return (unsigned short)((u + 0x7fffu + ((u >> 16) & 1u)) >> 16);
}
__device__ __forceinline__ float bflo(unsigned v) { return __uint_as_float(v << 16); }
__device__ __forceinline__ float bfhi(unsigned v) { return __uint_as_float(v & 0xffff0000u); }

// ---- launch 1 (scatA ∥ prep): blocks [0,NBLK) run the R7-validated
// hist+reserve+scatter; blocks [NBLK, NBLK+XB2) stream x -> bf16 xh UNSCALED
// (dinv applied later in agg1 as FMA — removes the prep->csr dependency);
// remaining WB blocks pack W1/W2. The streaming blocks fill CU idle time
// under scatA's latency/atomic-bound phases. ----
__global__ __launch_bounds__(256) void k_scatprep(
    const int* __restrict__ row, const int* __restrict__ col,
    int* __restrict__ bcur, unsigned* __restrict__ rec,
    const float4* __restrict__ x, uint2* __restrict__ xh,
    const float* __restrict__ W1, const float* __restrict__ W2,
    __hip_bfloat16* __restrict__ W1p, __hip_bfloat16* __restrict__ W2p) {
    if (blockIdx.x < NBLK) {
        __shared__ int lh[NBUK];     // local count, then local cursor
        __shared__ int lbase[NBUK];  // reserved global base per bucket
        for (int i = threadIdx.x; i < NBUK; i += 256) lh[i] = 0;
        __syncthreads();
        const int e0 = blockIdx.x * CHUNK;
        const int e1 = min(e0 + CHUNK, EE);
        for (int e = e0 + threadIdx.x; e < e1; e += 256) {
            int c = col[e];
            if ((unsigned)c < (unsigned)NN) atomicAdd(&lh[c >> 8], 1);
        }
        __syncthreads();
        for (int i = threadIdx.x; i < NBUK; i += 256) {
            int cn = lh[i];
            lbase[i] = cn ? atomicAdd(&bcur[i], cn) : 0;   // range reservation
            lh[i] = 0;                                     // reuse as cursor
        }
        __syncthreads();
        for (int e = e0 + threadIdx.x; e < e1; e += 256) {
            int r = row[e], c = col[e];                    // col re-read hits L1/L2
            if ((unsigned)c < (unsigned)NN) {
                int b = c >> 8;
                int pos = lbase[b] + atomicAdd(&lh[b], 1); // LDS atomic
                if (pos < DCAP)
                    rec[(size_t)b * DCAP + pos] =
                        ((unsigned)r & 0xFFFFFFu) | ((unsigned)(c & 255) << 24);
            }
        }
    } else if (blockIdx.x < NBLK + XB2) {
        int idx = (blockIdx.x - NBLK) * 256 + threadIdx.x;  // NN*32 float4s exact
        float4 v = x[idx];
        uint2 o;
        o.x = (unsigned)f2bf(v.x) | ((unsigned)f2bf(v.y) << 16);
        o.y = (unsigned)f2bf(v.z) | ((unsigned)f2bf(v.w) << 16);
        xh[idx] = o;
    } else {
        int idx = (blockIdx.x - NBLK - XB2) * 256 + threadIdx.x;
        if (idx < F1 * F2) {
            int k = idx / F2, c = idx - (idx / F2) * F2;
            int k8 = k >> 3, j = k & 7;
            W1p[((size_t)(k8 * F2 + c) << 3) + j] = __float2bfloat16(W1[(size_t)k * F2 + c]);
        } else {                               // grid exact: idx < F1*F2 + F2*48
            int i2 = idx - F1 * F2;
            int k = i2 / 48, c = i2 - (i2 / 48) * 48;
            int k8 = k >> 3, j = k & 7;
            float v = (c < F3) ? W2[(size_t)k * F3 + c] : 0.0f;
            W2p[((size_t)(k8 * 48 + c) << 3) + j] = __float2bfloat16(v);
        }
    }
}

// ---- pass 2: bucket -> CSR; rec chunk cached in LDS (single global read);
// cnt via LDS histogram; cursor(end)=b*DCAP+excl+cnt; dinv. ----
__global__ __launch_bounds__(256) void k_csr(const int* __restrict__ bcur,
                                             const unsigned* __restrict__ rec,
                                             int* __restrict__ eidx,
                                             int* __restrict__ cnt,
                                             int* __restrict__ cursor,
                                             float* __restrict__ dinv) {
    __shared__ int lcnt[256];
    __shared__ int s[256];
    __shared__ int lcur[256];
    __shared__ unsigned lrec[DCAP];   // 16 KB cached records
    __shared__ int lde[DCAP];         // 16 KB sorted rows
    const int b = blockIdx.x;
    const int tid = threadIdx.x;
    lcnt[tid] = 0;
    __syncthreads();
    const int base = b * DCAP;
    const int nb = min(bcur[b], DCAP);
    for (int j = tid; j < nb; j += 256) {
        unsigned v = rec[(size_t)base + j];
        lrec[j] = v;
        atomicAdd(&lcnt[v >> 24], 1);
    }
    __syncthreads();
    int cv = lcnt[tid];
    s[tid] = cv;
    __syncthreads();
    int acc = cv;
    for (int d = 1; d < 256; d <<= 1) {
        int add = (tid >= d) ? s[tid - d] : 0;
        __syncthreads();
        acc += add;
        s[tid] = acc;
        __syncthreads();
    }
    int excl = acc - cv;
    lcur[tid] = excl;
    const int node = (b << 8) + tid;
    if (node < NN) {
        cnt[node] = cv;
        cursor[node] = base + excl + cv;            // END cursor (start = end - cnt)
        dinv[node] = rsqrtf((float)(cv + 1));       // +1 self-loop
    }
    __syncthreads();
    for (int j = tid; j < nb; j += 256) {
        unsigned v = lrec[j];
        int pos = atomicAdd(&lcur[v >> 24], 1);     // LDS atomic
        lde[pos] = (int)(v & 0xFFFFFFu);
    }
    __syncthreads();
    for (int j = tid; j < nb; j += 256) eidx[base + j] = lde[j];
}

// ---- layer-1 pull aggregation (xh unscaled -> per-row dinv FMA; same VALU
// count as the add version: v_fmac vs v_add. dinv[r] loads are wave-uniform
// broadcasts, L2-resident (400 KB). ----
__global__ __launch_bounds__(256) void k_agg1(const int* __restrict__ cursor,
                                              const int* __restrict__ cnt,
                                              const int* __restrict__ eidx,
                                              const float* __restrict__ dinv,
                                              const unsigned* __restrict__ xh,
                                              unsigned* __restrict__ agg) {
    int node = blockIdx.x * 4 + (threadIdx.x >> 6);
    int lane = threadIdx.x & 63;
    if (node >= NN) return;
    float dn = dinv[node];
    unsigned vs = xh[((size_t)node << 6) + lane];
    float a0 = bflo(vs) * dn, a1 = bfhi(vs) * dn;   // self-loop: x[node]*dinv[node]
    int n = cnt[node];
    int s = cursor[node] - n;
    int k = 0;
    for (; k + 7 < n; k += 8) {
        int r0 = eidx[s + k + 0], r1 = eidx[s + k + 1];
        int r2 = eidx[s + k + 2], r3 = eidx[s + k + 3];
        int r4 = eidx[s + k + 4], r5 = eidx[s + k + 5];
        int r6 = eidx[s + k + 6], r7 = eidx[s + k + 7];
        float d0 = dinv[r0], d1 = dinv[r1], d2 = dinv[r2], d3 = dinv[r3];
        float d4 = dinv[r4], d5 = dinv[r5], d6 = dinv[r6], d7 = dinv[r7];
        unsigned v0 = xh[((size_t)r0 << 6) + lane];
        unsigned v1 = xh[((size_t)r1 << 6) + lane];
        unsigned v2 = xh[((size_t)r2 << 6) + lane];
        unsigned v3 = xh[((size_t)r3 << 6) + lane];
        unsigned v4 = xh[((size_t)r4 << 6) + lane];
        unsigned v5 = xh[((size_t)r5 << 6) + lane];
        unsigned v6 = xh[((size_t)r6 << 6) + lane];
        unsigned v7 = xh[((size_t)r7 << 6) + lane];
        a0 += bflo(v0) * d0; a1 += bfhi(v0) * d0;
        a0 += bflo(v1) * d1; a1 += bfhi(v1) * d1;
        a0 += bflo(v2) * d2; a1 += bfhi(v2) * d2;
        a0 += bflo(v3) * d3; a1 += bfhi(v3) * d3;
        a0 += bflo(v4) * d4; a1 += bfhi(v4) * d4;
        a0 += bflo(v5) * d5; a1 += bfhi(v5) * d5;
        a0 += bflo(v6) * d6; a1 += bfhi(v6) * d6;
        a0 += bflo(v7) * d7; a1 += bfhi(v7) * d7;
    }
    for (; k + 3 < n; k += 4) {
        int r0 = eidx[s + k + 0], r1 = eidx[s + k + 1];
        int r2 = eidx[s + k + 2], r3 = eidx[s + k + 3];
        float d0 = dinv[r0], d1 = dinv[r1], d2 = dinv[r2], d3 = dinv[r3];
        unsigned v0 = xh[((size_t)r0 << 6) + lane];
        unsigned v1 = xh[((size_t)r1 << 6) + lane];
        unsigned v2 = xh[((size_t)r2 << 6) + lane];
        unsigned v3 = xh[((size_t)r3 << 6) + lane];
        a0 += bflo(v0) * d0; a1 += bfhi(v0) * d0;
        a0 += bflo(v1) * d1; a1 += bfhi(v1) * d1;
        a0 += bflo(v2) * d2; a1 += bfhi(v2) * d2;
        a0 += bflo(v3) * d3; a1 += bfhi(v3) * d3;
    }
    for (; k < n; ++k) {
        int r0 = eidx[s + k];
        float d0 = dinv[r0];
        unsigned v0 = xh[((size_t)r0 << 6) + lane];
        a0 += bflo(v0) * d0; a1 += bfhi(v0) * d0;
    }
    agg[((size_t)node << 6) + lane] = (unsigned)f2bf(a0 * dn) | ((unsigned)f2bf(a1 * dn) << 16);
}

// ---- fused MFMA GEMM1 + ReLU + GEMM2; tg rows PACKED to 40 bf16 (80B, 16B-aligned) ----
__global__ __launch_bounds__(256) void k_gemm_mfma(
    const __hip_bfloat16* __restrict__ agg, const __hip_bfloat16* __restrict__ W1p,
    const float* __restrict__ b1, const __hip_bfloat16* __restrict__ W2p,
    const float* __restrict__ dinv, unsigned short* __restrict__ tg) {
    __shared__ __hip_bfloat16 h_s[MROWS][F2 + 8];   // 33 KB
    const int i0   = blockIdx.x * MROWS;
    const int wave = threadIdx.x >> 6;
    const int lane = threadIdx.x & 63;
    const int m = lane & 15, q = lane >> 4;
    const int rowA = i0 + wave * 16 + m;

    f32x4 acc[16];
#pragma unroll
    for (int c = 0; c < 16; ++c) acc[c] = (f32x4){0.f, 0.f, 0.f, 0.f};

#pragma unroll
    for (int s = 0; s < 4; ++s) {           // k = 32s + 8q + j
        bf16x8 a;
#pragma unroll
        for (int j = 0; j < 8; ++j) a[j] = (__bf16)0.0f;
        if (rowA < NN) a = *(const bf16x8*)(agg + (size_t)rowA * F1 + s * 32 + q * 8);
        const __hip_bfloat16* bp = W1p + ((size_t)(4 * s + q) * F2) * 8;
#pragma unroll
        for (int c = 0; c < 16; ++c) {
            bf16x8 b = *(const bf16x8*)(bp + ((size_t)(c * 16 + m) << 3));
            acc[c] = __builtin_amdgcn_mfma_f32_16x16x32_bf16(a, b, acc[c], 0, 0, 0);
        }
    }

#pragma unroll
    for (int c = 0; c < 16; ++c) {
        int col = c * 16 + m;
        float bj = b1[col];
#pragma unroll
        for (int r = 0; r < 4; ++r) {
            int lr = wave * 16 + q * 4 + r;
            h_s[lr][col] = __float2bfloat16(fmaxf(acc[c][r] + bj, 0.0f));
        }
    }
    __syncthreads();

    f32x4 acc2[3];
#pragma unroll
    for (int c = 0; c < 3; ++c) acc2[c] = (f32x4){0.f, 0.f, 0.f, 0.f};

#pragma unroll
    for (int s = 0; s < 8; ++s) {
        bf16x8 a = *(const bf16x8*)(&h_s[wave * 16 + m][s * 32 + q * 8]);
        const __hip_bfloat16* bp = W2p + ((size_t)(4 * s + q) * 48) * 8;
#pragma unroll
        for (int c = 0; c < 3; ++c) {
            bf16x8 b = *(const bf16x8*)(bp + ((size_t)(c * 16 + m) << 3));
            acc2[c] = __builtin_amdgcn_mfma_f32_16x16x32_bf16(a, b, acc2[c], 0, 0, 0);
        }
    }

#pragma unroll
    for (int c = 0; c < 3; ++c) {
        int col = c * 16 + m;
        if (col < F3) {
#pragma unroll
            for (int r = 0; r < 4; ++r) {
                int grow = i0 + wave * 16 + q * 4 + r;
                if (grow < NN)
                    tg[(size_t)grow * F3 + col] = f2bf(acc2[c][r] * dinv[grow]);
            }
        }
    }
}

// ---- layer-2 pull aggregation: 6 nodes/wave (10-lane groups), uint2 per lane
// over packed 80B rows; 3.8KB in flight per wave (R10-validated). ----
__global__ __launch_bounds__(256) void k_agg2(const int* __restrict__ cursor,
                                              const int* __restrict__ cnt,
                                              const int* __restrict__ eidx,
                                              const float* __restrict__ dinv,
                                              const unsigned short* __restrict__ tg,
                                              const float* __restrict__ b2,
                                              float* __restrict__ out) {
    const int wave = threadIdx.x >> 6;
    const int lane = threadIdx.x & 63;
    const int g = lane / 10;                        // 0..6 (6 => idle)
    const int t = lane - g * 10;                    // uint2 index in row
    const int node = blockIdx.x * 24 + wave * 6 + g;
    if (g >= 6 || node >= NN) return;
    const uint2* __restrict__ tg2 = (const uint2*)tg;

    uint2 v = tg2[(size_t)node * 10 + t];           // self term
    float a0 = bflo(v.x), a1 = bfhi(v.x), a2 = bflo(v.y), a3 = bfhi(v.y);
    const int n = cnt[node];
    const int s = cursor[node] - n;
    int k = 0;
    for (; k + 7 < n; k += 8) {
        int r0 = eidx[s + k + 0], r1 = eidx[s + k + 1];
        int r2 = eidx[s + k + 2], r3 = eidx[s + k + 3];
        int r4 = eidx[s + k + 4], r5 = eidx[s + k + 5];
        int r6 = eidx[s + k + 6], r7 = eidx[s + k + 7];
        uint2 v0 = tg2[(size_t)r0 * 10 + t];
        uint2 v1 = tg2[(size_t)r1 * 10 + t];
        uint2 v2 = tg2[(size_t)r2 * 10 + t];
        uint2 v3 = tg2[(size_t)r3 * 10 + t];
        uint2 v4 = tg2[(size_t)r4 * 10 + t];
        uint2 v5 = tg2[(size_t)r5 * 10 + t];
        uint2 v6 = tg2[(size_t)r6 * 10 + t];
        uint2 v7 = tg2[(size_t)r7 * 10 + t];
        a0 += bflo(v0.x); a1 += bfhi(v0.x); a2 += bflo(v0.y); a3 += bfhi(v0.y);
        a0 += bflo(v1.x); a1 += bfhi(v1.x); a2 += bflo(v1.y); a3 += bfhi(v1.y);
        a0 += bflo(v2.x); a1 += bfhi(v2.x); a2 += bflo(v2.y); a3 += bfhi(v2.y);
        a0 += bflo(v3.x); a1 += bfhi(v3.x); a2 += bflo(v3.y); a3 += bfhi(v3.y);
        a0 += bflo(v4.x); a1 += bfhi(v4.x); a2 += bflo(v4.y); a3 += bfhi(v4.y);
        a0 += bflo(v5.x); a1 += bfhi(v5.x); a2 += bflo(v5.y); a3 += bfhi(v5.y);
        a0 += bflo(v6.x); a1 += bfhi(v6.x); a2 += bflo(v6.y); a3 += bfhi(v6.y);
        a0 += bflo(v7.x); a1 += bfhi(v7.x); a2 += bflo(v7.y); a3 += bfhi(v7.y);
    }
    for (; k + 3 < n; k += 4) {
        int r0 = eidx[s + k + 0], r1 = eidx[s + k + 1];
        int r2 = eidx[s + k + 2], r3 = eidx[s + k + 3];
        uint2 v0 = tg2[(size_t)r0 * 10 + t];
        uint2 v1 = tg2[(size_t)r1 * 10 + t];
        uint2 v2 = tg2[(size_t)r2 * 10 + t];
        uint2 v3 = tg2[(size_t)r3 * 10 + t];
        a0 += bflo(v0.x); a1 += bfhi(v0.x); a2 += bflo(v0.y); a3 += bfhi(v0.y);
        a0 += bflo(v1.x); a1 += bfhi(v1.x); a2 += bflo(v1.y); a3 += bfhi(v1.y);
        a0 += bflo(v2.x); a1 += bfhi(v2.x); a2 += bflo(v2.y); a3 += bfhi(v2.y);
        a0 += bflo(v3.x); a1 += bfhi(v3.x); a2 += bflo(v3.y); a3 += bfhi(v3.y);
    }
    for (; k < n; ++k) {
        uint2 v0 = tg2[(size_t)eidx[s + k] * 10 + t];
        a0 += bflo(v0.x); a1 += bfhi(v0.x); a2 += bflo(v0.y); a3 += bfhi(v0.y);
    }
    float d = dinv[node];
    float4 bb = *(const float4*)(b2 + 4 * t);
    float4 o;
    o.x = a0 * d + bb.x;
    o.y = a1 * d + bb.y;
    o.z = a2 * d + bb.z;
    o.w = a3 * d + bb.w;
    *(float4*)(out + (size_t)node * F3 + 4 * t) = o;
}

extern "C" void kernel_launch(void* const* d_in, const int* in_sizes, int n_in,
                              void* d_out, int out_size, void* d_ws, size_t ws_size,
                              hipStream_t stream) {
    const float* x  = (const float*)d_in[0];
    const int*   ei = (const int*)d_in[1];
    const float* W1 = (const float*)d_in[2];
    const float* b1 = (const float*)d_in[3];
    const float* W2 = (const float*)d_in[4];
    const float* b2 = (const float*)d_in[5];
    float* out = (float*)d_out;

    const int* row = ei;
    const int* col = ei + EE;

    // ws: cnt[N] | cursor[N] | dinv[N] | bcur[NBUK] | pad | eidx[NBUK*DCAP]
    //     | xh[N*64 u32] | agg[N*64 u32] | W1p | W2p        ~59 MB
    // overlays: rec (NBUK*DCAP u32 = 6.4MB) on agg (dead until k_agg1);
    // tg (N*40 bf16 packed, 8MB) on xh (dead after k_agg1; agg1/gemm separate
    // launches — round-4 lesson).
    // ints before eidx: 3*100000 + 391 + 9 = 300400 -> eidx 16B-aligned;
    // ints before xh: 300400 + 1601536 = 1901936 -> xh byte 7607744 %16==0.
    int* cnt     = (int*)d_ws;
    int* cursor  = cnt + NN;
    float* dinv  = (float*)(cursor + NN);
    int* bcur    = (int*)(dinv + NN);
    int* eidx    = bcur + NBUK + 9;            // pad -> 16B alignment
    unsigned* xh  = (unsigned*)(eidx + NBUK * DCAP);
    unsigned* agg = xh + (size_t)NN * 64;
    unsigned* rec = agg;                               // overlay on agg (6.4MB)
    unsigned short* tg = (unsigned short*)xh;          // overlay on xh (8MB)
    __hip_bfloat16* W1p = (__hip_bfloat16*)(agg + (size_t)NN * 64);
    __hip_bfloat16* W2p = W1p + (size_t)F1 * F2;

    hipMemsetAsync(bcur, 0, NBUK * sizeof(int), stream);
    k_scatprep<<<NBLK + XB2 + WB, 256, 0, stream>>>(
        row, col, bcur, rec, (const float4*)x, (uint2*)xh, W1, W2, W1p, W2p);
    k_csr<<<NBUK, 256, 0, stream>>>(bcur, rec, eidx, cnt, cursor, dinv);

    k_agg1<<<(NN + 3) / 4, 256, 0, stream>>>(cursor, cnt, eidx, dinv, xh, agg);
    k_gemm_mfma<<<(NN + MROWS - 1) / MROWS, 256, 0, stream>>>(
        (const __hip_bfloat16*)agg, W1p, b1, W2p, dinv, tg);
    k_agg2<<<(NN + 23) / 24, 256, 0, stream>>>(cursor, cnt, eidx, dinv, tg, b2, out);
}